// Round 13
// baseline (250.719 us; speedup 1.0000x reference)
//
#include <hip/hip_runtime.h>

#define BN_EPS 1e-5f

typedef __attribute__((ext_vector_type(8))) short bf16x8;
typedef __attribute__((ext_vector_type(4))) float f32x4;

__device__ __forceinline__ unsigned short f2bf(float f) {
    unsigned u = __float_as_uint(f);
    return (unsigned short)((u + 0x7fffu + ((u >> 16) & 1u)) >> 16);   // RNE
}
__device__ __forceinline__ unsigned packbf(float lo, float hi) {
    return ((unsigned)f2bf(hi) << 16) | (unsigned)f2bf(lo);
}
__device__ __forceinline__ float bf2f(unsigned short u) {
    return __uint_as_float((unsigned)u << 16);
}
// load 8 consecutive fp32 weights, convert to bf16x8 in-register
__device__ __forceinline__ bf16x8 ldw8(const float* p) {
    float4 a = *(const float4*)p;
    float4 b = *(const float4*)(p + 4);
    union { unsigned u[4]; bf16x8 v; } r;
    r.u[0] = packbf(a.x, a.y);
    r.u[1] = packbf(a.z, a.w);
    r.u[2] = packbf(b.x, b.y);
    r.u[3] = packbf(b.z, b.w);
    return r.v;
}

// ---------------------------------------------------------------------------
// Mirrors are CHANNEL-LAST: [b][H][W][cp=32] u32 (cp k = channels 2k,2k+1
// pair-packed bf16).  enc logits channel-last [b][h][w][100] ushort.
// R26: conv3x3 async-STAGE split — kb=1's global loads issued into REGISTERS
// before kb=0's MFMA phase (latency hides under MFMA), written to LDS after.
// (LDS double-buffer would halve blocks/CU — register split keeps LDS 20736.)
// ---------------------------------------------------------------------------

// ---------------------------------------------------------------------------
// conv3x3 body (bf16 MFMA 16x16x32, C_in=64, fp32 acc).  LDS 20736 B.
// Split-K; channel-last packed input.  OBF16: enc-logit bf16 channel-last
// output.  CPB stays 1 (R1/R2 VGPR cliff).
// ---------------------------------------------------------------------------
template<int COP, int CSPLIT, int MODE, bool OBF16>
__device__ __forceinline__
void conv3x3_body(int rem, int TX, unsigned short* xs,
                  const unsigned* __restrict__ xp,
                  const unsigned short* __restrict__ wt,
                  const float* __restrict__ p0, const float* __restrict__ p1,
                  const float* __restrict__ p2, const float* __restrict__ p3,
                  float* __restrict__ out, unsigned short* __restrict__ out_us,
                  int H, int W, int C_out)
{
    constexpr int NP = 324;
    constexpr int CT = COP / 16;
    static_assert(CT == CSPLIT, "CPB must be 1 (R1/R2 VGPR cliff)");

    int cs = rem % CSPLIT;
    int b  = (rem / CSPLIT) & 3;
    int t  = rem / (CSPLIT * 4);
    int x0 = (t % TX) * 16, y0 = (t / TX) * 16;

    int tid  = threadIdx.x;
    int lane = tid & 63, wid = tid >> 6;
    int lrow = lane >> 4, lcol = lane & 15;
    int HWp = H * W;

    int co0 = cs * 16;
    bool colok = (x0 + lcol) < W;

    f32x4 accA[2], accB[2];
#pragma unroll
    for (int rr = 0; rr < 2; ++rr) {
        accA[rr] = (f32x4){0.f, 0.f, 0.f, 0.f};
        accB[rr] = (f32x4){0.f, 0.f, 0.f, 0.f};
    }

    unsigned int* wsl = (unsigned int*)xs;
    const unsigned* xb = xp + (size_t)b * HWp * 32;

    // ---- stage kb=0 (pairs 0..15) straight to LDS ----
    for (int it = tid; it < NP * 4; it += 256) {
        int p = it >> 2, g = it & 3;
        int py = p / 18, px = p - py * 18;
        int gy = y0 + py - 1, gx = x0 + px - 1;
        uint4 v = make_uint4(0u, 0u, 0u, 0u);
        if (gy >= 0 && gy < H && gx >= 0 && gx < W)
            v = *(const uint4*)(xb + ((size_t)gy * W + gx) * 32 + g * 4);
        *(uint4*)(wsl + ((size_t)g * NP + p) * 4) = v;
    }
    // ---- R26: issue kb=1 (pairs 16..31) loads into registers NOW;
    //      the wait lands after kb=0's MFMA phase ----
    uint4 pf[6];
#pragma unroll
    for (int j = 0; j < 6; ++j) {
        pf[j] = make_uint4(0u, 0u, 0u, 0u);
        int it = tid + j * 256;
        if (it < NP * 4) {
            int p = it >> 2, g = it & 3;
            int py = p / 18, px = p - py * 18;
            int gy = y0 + py - 1, gx = x0 + px - 1;
            if (gy >= 0 && gy < H && gx >= 0 && gx < W)
                pf[j] = *(const uint4*)(xb + ((size_t)gy * W + gx) * 32 + 16 + g * 4);
        }
    }
    __syncthreads();

    auto mfma_phase = [&](int kb) {
        bf16x8 a[9];
        const unsigned short* wl = wt + ((size_t)co0 + lcol) * 64 + kb * 32 + lrow * 8;
#pragma unroll
        for (int t9 = 0; t9 < 9; ++t9)
            a[t9] = *(const bf16x8*)(wl + (size_t)t9 * COP * 64);
#pragma unroll
        for (int rr = 0; rr < 2; ++rr) {
            int r0 = wid + rr * 8;
#pragma unroll
            for (int t9 = 0; t9 < 9; ++t9) {
                int dy = t9 / 3, dx = t9 - dy * 3;
                int g0 = lrow * NP + (r0 + dy) * 18 + lcol + dx;
                bf16x8 b0 = *(const bf16x8*)(xs + (size_t)g0 * 8);
                accA[rr] = __builtin_amdgcn_mfma_f32_16x16x32_bf16(a[t9], b0, accA[rr], 0, 0, 0);
                bf16x8 b1 = *(const bf16x8*)(xs + ((size_t)g0 + 4 * 18) * 8);
                accB[rr] = __builtin_amdgcn_mfma_f32_16x16x32_bf16(a[t9], b1, accB[rr], 0, 0, 0);
            }
        }
    };

    mfma_phase(0);
    __syncthreads();               // all kb=0 LDS reads done
    // ---- write prefetched kb=1 tile to LDS ----
#pragma unroll
    for (int j = 0; j < 6; ++j) {
        int it = tid + j * 256;
        if (it < NP * 4) {
            int p = it >> 2, g = it & 3;
            *(uint4*)(wsl + ((size_t)g * NP + p) * 4) = pf[j];
        }
    }
    __syncthreads();
    mfma_phase(1);

    // ---- epilogue: BN/bias + store ----
    float sc[4], sh[4];
#pragma unroll
    for (int rg = 0; rg < 4; ++rg) {
        int co = co0 + lrow * 4 + rg;
        int cc = (co < C_out) ? co : 0;
        if (MODE == 0) { sc[rg] = 1.f; sh[rg] = p0[cc]; }
        else {
            float inv = p0[cc] * rsqrtf(p3[cc] + BN_EPS);
            sc[rg] = inv; sh[rg] = p1[cc] - p2[cc] * inv;
        }
    }
#pragma unroll
    for (int rr = 0; rr < 2; ++rr) {
        int r0 = wid + rr * 8;
        int yA = y0 + r0, yB = y0 + r0 + 4;
        if (OBF16) {
            if (colok) {
                if (yA < H) {
                    unsigned short* oc = out_us + (((size_t)b * H + yA) * W + x0 + lcol) * 100;
#pragma unroll
                    for (int rg = 0; rg < 4; ++rg) {
                        int co = co0 + lrow * 4 + rg;
                        if (co < C_out) oc[co] = f2bf(accA[rr][rg] * sc[rg] + sh[rg]);
                    }
                }
                if (yB < H) {
                    unsigned short* oc = out_us + (((size_t)b * H + yB) * W + x0 + lcol) * 100;
#pragma unroll
                    for (int rg = 0; rg < 4; ++rg) {
                        int co = co0 + lrow * 4 + rg;
                        if (co < C_out) oc[co] = f2bf(accB[rr][rg] * sc[rg] + sh[rg]);
                    }
                }
            }
        } else {
#pragma unroll
            for (int rg = 0; rg < 4; ++rg) {
                int co = co0 + lrow * 4 + rg;
                if (colok && co < C_out) {
                    float* oc = out + (((size_t)b * C_out + co) * H) * W + x0 + lcol;
                    if (yA < H) oc[(size_t)yA * W] = accA[rr][rg] * sc[rg] + sh[rg];
                    if (yB < H) oc[(size_t)yB * W] = accB[rr][rg] * sc[rg] + sh[rg];
                }
            }
        }
    }
}

// enc conv3x3 (channel-last packed in, bf16 channel-last out) + independent
// fpn level in ONE dispatch.
__global__ __launch_bounds__(256, 6)
void enc_fpn(int encBlocks,
             const unsigned* __restrict__ cxp, const unsigned short* __restrict__ wt_e,
             const float* __restrict__ g, const float* __restrict__ bt,
             const float* __restrict__ m, const float* __restrict__ v,
             unsigned short* __restrict__ enc_us, int He, int We, int TXe,
             const unsigned* __restrict__ xp, const unsigned short* __restrict__ wt_f,
             const float* __restrict__ bias, float* __restrict__ fout,
             int Hf, int Wf, int TXf)
{
    __shared__ unsigned short xs[4 * 324 * 8];
    int f = blockIdx.x;
    if (f < encBlocks)
        conv3x3_body<112, 7, 1, true>(f, TXe, xs, cxp, wt_e,
                                      g, bt, m, v, nullptr, enc_us, He, We, 100);
    else
        conv3x3_body<64, 4, 0, false>(f - encBlocks, TXf, xs, xp, wt_f,
                                      bias, nullptr, nullptr, nullptr, fout, nullptr, Hf, Wf, 64);
}

// final fpn: level0 only.  grid (960)
__global__ __launch_bounds__(256, 6)
void fpn_multi(const unsigned* __restrict__ l0p, const unsigned short* __restrict__ wt0,
               const float* __restrict__ b0, float* __restrict__ o0)
{
    __shared__ unsigned short xs[4 * 324 * 8];
    conv3x3_body<64, 4, 0, false>(blockIdx.x, 10, xs, l0p, wt0,
                                  b0, nullptr, nullptr, nullptr, o0, nullptr, 96, 160, 64);
}

// ---------------------------------------------------------------------------
// conv1x1 body (bf16 MFMA GEMM).  fp32 weights converted in-register (ldw8);
// output: channel-last bf16 pair-packed mirror.  INPK: channel-last packed
// input.  R25: DOUBLE-BUFFERED staging (stage(k+1) before MFMA(k)).
// ---------------------------------------------------------------------------
template<int C_IN, int NPX, int MODE, bool INPK>
__device__ __forceinline__
void conv1x1_body(int f, unsigned short* xs,
                  const float* __restrict__ x, const unsigned* __restrict__ xp,
                  const float* __restrict__ wf,
                  const float* __restrict__ p0, const float* __restrict__ p1,
                  const float* __restrict__ p2, const float* __restrict__ p3,
                  unsigned* __restrict__ outp, int HW)
{
    constexpr int NT = NPX / 16;
    constexpr int QUADS = NPX / 4;          // pow2
    constexpr int BUFU = NPX * 16;          // u32 per LDS buffer
    constexpr int NK = C_IN / 32;
    int nb = HW / NPX;
    int px0 = (f % nb) * NPX;
    int b   = f / nb;

    int tid = threadIdx.x;
    int lane = tid & 63, wid = tid >> 6;
    int lrow = lane >> 4, lcol = lane & 15;
    const float*    xb  = INPK ? nullptr : x + (size_t)b * C_IN * HW + px0;
    const unsigned* xpb = INPK ? xp + ((size_t)b * HW + px0) * 32 : nullptr;
    unsigned* xsu = (unsigned*)xs;

    auto stage = [&](int cc, int buf) {
        unsigned* base = xsu + buf * BUFU;
        if (INPK) {
            for (int it = tid; it < NPX * 4; it += 256) {
                int px = it >> 2, g = it & 3;
                uint4 v = *(const uint4*)(xpb + (size_t)px * 32 + cc / 2 + g * 4);
                *(uint4*)(base + ((size_t)g * NPX + px) * 4) = v;
            }
        } else {
            for (int j = tid; j < 16 * QUADS; j += 256) {
                int q  = j & (QUADS - 1);
                int cp = j / QUADS;
                int px = q * 4;
                const float* s0 = xb + (size_t)(cc + 2 * cp) * HW + px;
                float4 v0 = *(const float4*)s0;
                float4 v1 = *(const float4*)(s0 + HW);
                unsigned* wv = base + ((size_t)(cp >> 2) * NPX + px) * 4 + (cp & 3);
                wv[0]  = packbf(v0.x, v1.x);
                wv[4]  = packbf(v0.y, v1.y);
                wv[8]  = packbf(v0.z, v1.z);
                wv[12] = packbf(v0.w, v1.w);
            }
        }
    };

    f32x4 acc[NT];
#pragma unroll
    for (int nt = 0; nt < NT; ++nt) acc[nt] = (f32x4){0.f, 0.f, 0.f, 0.f};

    stage(0, 0);
#pragma unroll 1
    for (int k = 0; k < NK; ++k) {
        __syncthreads();
        if (k + 1 < NK) stage((k + 1) * 32, (k + 1) & 1);   // prefetch next step

        bf16x8 a = ldw8(wf + (size_t)(wid * 16 + lcol) * C_IN + k * 32 + lrow * 8);
        const unsigned short* rb = xs + (size_t)(k & 1) * BUFU * 2;
#pragma unroll
        for (int nt = 0; nt < NT; ++nt) {
            bf16x8 bf = *(const bf16x8*)(rb + ((size_t)lrow * NPX + nt * 16 + lcol) * 8);
            acc[nt] = __builtin_amdgcn_mfma_f32_16x16x32_bf16(a, bf, acc[nt], 0, 0, 0);
        }
    }

    // epilogue: channel-last mirror write — one uint2 per nt.
    float sc[4], sh[4];
#pragma unroll
    for (int rg = 0; rg < 4; ++rg) {
        int co = wid * 16 + lrow * 4 + rg;
        if (MODE == 0) { sc[rg] = 1.f; sh[rg] = p0[co]; }
        else {
            float inv = p0[co] * rsqrtf(p3[co] + BN_EPS);
            sc[rg] = inv; sh[rg] = p1[co] - p2[co] * inv;
        }
    }
    unsigned* pp = outp + ((size_t)b * HW + px0) * 32 + wid * 8 + lrow * 2;
#pragma unroll
    for (int nt = 0; nt < NT; ++nt) {
        float r[4];
#pragma unroll
        for (int rg = 0; rg < 4; ++rg) {
            r[rg] = acc[nt][rg] * sc[rg] + sh[rg];
            if (MODE == 1) r[rg] = fmaxf(r[rg], 0.f);
        }
        uint2 pk = make_uint2(packbf(r[0], r[1]), packbf(r[2], r[3]));
        *(uint2*)(pp + (size_t)(nt * 16 + lcol) * 32) = pk;
    }
}

// standalone conv1x1 (comp layers, channel-last packed in), grid (HW/NPX,1,B)
template<int C_IN, int NPX, int MODE, bool INPK>
__global__ __launch_bounds__(256, 4)
void conv1x1_mfma(const float* __restrict__ x, const unsigned* __restrict__ xp,
                  const float* __restrict__ wf,
                  const float* __restrict__ p0, const float* __restrict__ p1,
                  const float* __restrict__ p2, const float* __restrict__ p3,
                  unsigned* __restrict__ outp, int HW)
{
    __shared__ __align__(16) unsigned short xs[2 * 4 * NPX * 8];
    int nb = HW / NPX;
    int f = blockIdx.x + nb * blockIdx.z;
    conv1x1_body<C_IN, NPX, MODE, INPK>(f, xs, x, xp, wf, p0, p1, p2, p3, outp, HW);
}

// fused lateral convs + 3x3 weight prep backfill — ONE dispatch (894).
__global__ __launch_bounds__(256, 4)
void lat_prep(const float* __restrict__ x0, const float* __restrict__ w0,
              const float* __restrict__ b0, unsigned* __restrict__ lat0b,
              const float* __restrict__ x1, const float* __restrict__ w1,
              const float* __restrict__ b1, unsigned* __restrict__ lat1b,
              const float* __restrict__ x2, const float* __restrict__ w2,
              const float* __restrict__ b2, unsigned* __restrict__ lat2p,
              const float* __restrict__ f0w, const float* __restrict__ f1w,
              const float* __restrict__ f2w, const float* __restrict__ e0w,
              const float* __restrict__ e1w, unsigned short* __restrict__ wtb)
{
    __shared__ __align__(16) unsigned short xs[2 * 4 * 128 * 8];
    int f = blockIdx.x;
    if (f < 480)
        conv1x1_body<128, 128, 0, false>(f, xs, x0, nullptr, w0,
            b0, nullptr, nullptr, nullptr, lat0b, 15360);
    else if (f < 600)
        conv1x1_body<256, 128, 0, false>(f - 480, xs, x1, nullptr, w1,
            b1, nullptr, nullptr, nullptr, lat1b, 3840);
    else if (f < 660)
        conv1x1_body<512, 64, 0, false>(f - 600, xs, x2, nullptr, w2,
            b2, nullptr, nullptr, nullptr, lat2p, 960);
    else {
        int base = (f - 660) * 1024 + threadIdx.x;
#pragma unroll
        for (int t = 0; t < 4; ++t) {
            int i = base + t * 256;            // < 239616 exactly
            float v;
            if (i < 110592) {
                int z = i / 36864;
                int rem = i - z * 36864;
                int tap = rem / 4096;          // 64*64
                int r2 = rem - tap * 4096;
                int co = r2 >> 6, ci = r2 & 63;
                const float* src = (z == 0) ? f0w : (z == 1 ? f1w : f2w);
                v = src[((size_t)co * 64 + ci) * 9 + tap];
            } else {
                int j = i - 110592;
                int z = j / 64512;
                int rem = j - z * 64512;
                int tap = rem / 7168;          // 112*64
                int r2 = rem - tap * 7168;
                int co = r2 >> 6, ci = r2 & 63;
                const float* src = z ? e1w : e0w;
                v = (co < 100) ? src[((size_t)co * 64 + ci) * 9 + tap] : 0.f;
            }
            wtb[i] = f2bf(v);
        }
    }
}

// ---------------------------------------------------------------------------
// CARAFE (CGS=2).  channel-last src/base/dst; bf16 logits.
// grid: (2w/16, 2h/16, B * CGS), block 256
// ---------------------------------------------------------------------------
template<int CGS>
__global__ __launch_bounds__(256, 4)
void carafe_kernel(const unsigned* __restrict__ srcp,
                   const unsigned short* __restrict__ logits_us,
                   const unsigned* __restrict__ basep, unsigned* __restrict__ dstp,
                   int h, int w)
{
    constexpr int SW = 12, NPX = 144;
    constexpr int CH = 64 / CGS;     // channels per block
    constexpr int CP = CH / 2;       // channel-pairs per block
    constexpr int G  = CP / 4;       // uint4 groups per pixel
    constexpr int CS = CH + 4;
    __shared__ float ls[NPX * CS];

    int tid = threadIdx.x;
    int x0 = blockIdx.x * 16, y0 = blockIdx.y * 16;
    int b  = blockIdx.z / CGS;
    int cs = blockIdx.z % CGS;
    int H = 2 * h, W = 2 * w;
    int xs0 = (x0 >> 1) - 2, ys0 = (y0 >> 1) - 2;
    size_t hw = (size_t)h * w;
    const unsigned* sb = srcp + (size_t)b * hw * 32 + cs * CP;

    // stage: item = (p, g): uint4 of pairs cs*CP+4g..+3 at src pixel p.
    for (int i = tid; i < NPX * G; i += 256) {
        int p = i / G, g = i - (i / G) * G;
        int yy = p / SW, xx = p - yy * SW;
        int sy = ys0 + yy, sx = xs0 + xx;
        uint4 u = make_uint4(0u, 0u, 0u, 0u);
        if (sy >= 0 && sy < h && sx >= 0 && sx < w)
            u = *(const uint4*)(sb + ((size_t)sy * w + sx) * 32 + g * 4);
        float* lq = &ls[p * CS + g * 8];
        lq[0] = __uint_as_float(u.x << 16); lq[1] = __uint_as_float(u.x & 0xffff0000u);
        lq[2] = __uint_as_float(u.y << 16); lq[3] = __uint_as_float(u.y & 0xffff0000u);
        lq[4] = __uint_as_float(u.z << 16); lq[5] = __uint_as_float(u.z & 0xffff0000u);
        lq[6] = __uint_as_float(u.w << 16); lq[7] = __uint_as_float(u.w & 0xffff0000u);
    }
    __syncthreads();

    int lx = tid & 15, ty = tid >> 4;
    int x = x0 + lx, y = y0 + ty;
    int xw = x >> 1, yh = y >> 1;
    int par = (y & 1) * 2 + (x & 1);

    const unsigned short* lp = logits_us + ((size_t)b * hw + (size_t)yh * w + xw) * 100 + par;
    float l[25];
    float mx = -1e30f;
#pragma unroll
    for (int k = 0; k < 25; ++k) {
        l[k] = bf2f(lp[4 * k]);
        mx = fmaxf(mx, l[k]);
    }
    float s = 0.f;
#pragma unroll
    for (int k = 0; k < 25; ++k) {
        l[k] = __expf(l[k] - mx);
        s += l[k];
    }
    float invs = 1.f / s;
#pragma unroll
    for (int k = 0; k < 25; ++k) l[k] *= invs;

    int pb = (yh - ys0 - 2) * SW + (xw - xs0 - 2);

#pragma unroll 1
    for (int cg = 0; cg < CH / 16; ++cg) {
        float acc[16];
#pragma unroll
        for (int c = 0; c < 16; ++c) acc[c] = 0.f;
#pragma unroll
        for (int k = 0; k < 25; ++k) {
            int ti = k / 5, tj = k - ti * 5;
            const float* q = &ls[(pb + ti * SW + tj) * CS + cg * 16];
            float wk = l[k];
#pragma unroll
            for (int c = 0; c < 16; ++c)
                acc[c] = fmaf(wk, q[c], acc[c]);
        }
        // base/dst: 8 consecutive u32 at (px, pair base cs*CP+cg*8)
        size_t poff = (((size_t)b * H + y) * W + x) * 32 + cs * CP + cg * 8;
        uint4 ba = *(const uint4*)(basep + poff);
        uint4 bb = *(const uint4*)(basep + poff + 4);
        unsigned bu[8] = {ba.x, ba.y, ba.z, ba.w, bb.x, bb.y, bb.z, bb.w};
        unsigned ou[8];
#pragma unroll
        for (int j = 0; j < 8; ++j) {
            float n0 = __uint_as_float(bu[j] << 16) + acc[2 * j];
            float n1 = __uint_as_float(bu[j] & 0xffff0000u) + acc[2 * j + 1];
            ou[j] = packbf(n0, n1);
        }
        *(uint4*)(dstp + poff)     = make_uint4(ou[0], ou[1], ou[2], ou[3]);
        *(uint4*)(dstp + poff + 4) = make_uint4(ou[4], ou[5], ou[6], ou[7]);
    }
}

// ---------------------------------------------------------------------------
extern "C" void kernel_launch(void* const* d_in, const int* in_sizes, int n_in,
                              void* d_out, int out_size, void* d_ws, size_t ws_size,
                              hipStream_t stream)
{
    const float* x0      = (const float*)d_in[0];
    const float* lat0_w  = (const float*)d_in[1];
    const float* lat0_b  = (const float*)d_in[2];
    const float* fpn0_w  = (const float*)d_in[3];
    const float* fpn0_b  = (const float*)d_in[4];
    const float* x1      = (const float*)d_in[5];
    const float* lat1_w  = (const float*)d_in[6];
    const float* lat1_b  = (const float*)d_in[7];
    const float* fpn1_w  = (const float*)d_in[8];
    const float* fpn1_b  = (const float*)d_in[9];
    const float* x2      = (const float*)d_in[10];
    const float* lat2_w  = (const float*)d_in[11];
    const float* lat2_b  = (const float*)d_in[12];
    const float* fpn2_w  = (const float*)d_in[13];
    const float* fpn2_b  = (const float*)d_in[14];
    const float* u0_comp_w = (const float*)d_in[15];
    const float* u0_enc_w  = (const float*)d_in[16];
    const float* u0_comp_g  = (const float*)d_in[17];
    const float* u0_comp_bt = (const float*)d_in[18];
    const float* u0_comp_m  = (const float*)d_in[19];
    const float* u0_comp_v  = (const float*)d_in[20];
    const float* u0_enc_g   = (const float*)d_in[21];
    const float* u0_enc_bt  = (const float*)d_in[22];
    const float* u0_enc_m   = (const float*)d_in[23];
    const float* u0_enc_v   = (const float*)d_in[24];
    const float* u1_comp_w = (const float*)d_in[25];
    const float* u1_enc_w  = (const float*)d_in[26];
    const float* u1_comp_g  = (const float*)d_in[27];
    const float* u1_comp_bt = (const float*)d_in[28];
    const float* u1_comp_m  = (const float*)d_in[29];
    const float* u1_comp_v  = (const float*)d_in[30];
    const float* u1_enc_g   = (const float*)d_in[31];
    const float* u1_enc_bt  = (const float*)d_in[32];
    const float* u1_enc_m   = (const float*)d_in[33];
    const float* u1_enc_v   = (const float*)d_in[34];

    float* out = (float*)d_out;
    const size_t OUT0 = 4ull * 64 * 96 * 160;   // 3,932,160
    const size_t OUT1 = 4ull * 64 * 48 * 80;    //   983,040
    const size_t OUT2 = 4ull * 64 * 24 * 40;    //   245,760
    float* out0 = out;
    float* out1 = out + OUT0;
    float* out2 = out + OUT0 + OUT1;

    // workspace (mirrors are channel-last [b][H][W][cp=32] u32):
    unsigned* lat0b = (unsigned*)d_ws;                      // 1,966,080 u32
    unsigned* lat1b = lat0b + 1966080;                      //   491,520 u32
    unsigned short* wtb = (unsigned short*)(lat1b + 491520); // 239,616 bf16
    unsigned short* wt_fpn0 = wtb;
    unsigned short* wt_fpn1 = wtb + 36864;
    unsigned short* wt_fpn2 = wtb + 73728;
    unsigned short* wt_enc0 = wtb + 110592;
    unsigned short* wt_enc1 = wtb + 175104;
    unsigned* lat0p = (unsigned*)(wtb + 239616);            // 1,966,080 u32
    unsigned* lat1p = lat0p + 1966080;                      //   491,520 u32
    unsigned* lat2p = lat1p + 491520;                       //   122,880 u32
    unsigned* compp = lat2p + 122880;                       //   491,520 u32 (max)
    // out0 region doubles as scratch (fpn0 overwrites it LAST):
    unsigned short* enc_us = (unsigned short*)(out0 + OUT1); // enc logits bf16 CL

    dim3 blk(256);

    // 1) laterals (full-K, bias folded, mirror out) + 3x3 weight prep backfill
    lat_prep<<<dim3(894), blk, 0, stream>>>(
        x0, lat0_w, lat0_b, lat0b,
        x1, lat1_w, lat1_b, lat1b,
        x2, lat2_w, lat2_b, lat2p,
        fpn0_w, fpn1_w, fpn2_w, u0_enc_w, u1_enc_w, wtb);

    // 2) CARAFE u1: comp1 -> enc1(bf16) + fpn2 backfill -> carafe1
    conv1x1_mfma<64, 32, 1, true><<<dim3(30, 1, 4), blk, 0, stream>>>(
        nullptr, lat2p, u1_comp_w, u1_comp_g, u1_comp_bt, u1_comp_m, u1_comp_v,
        compp, 24 * 40);
    enc_fpn<<<dim3(264), blk, 0, stream>>>(168,
        compp, wt_enc1, u1_enc_g, u1_enc_bt, u1_enc_m, u1_enc_v, enc_us, 24, 40, 3,
        lat2p, wt_fpn2, fpn2_b, out2, 24, 40, 3);
    carafe_kernel<2><<<dim3(5, 3, 8), blk, 0, stream>>>(lat2p, enc_us, lat1b, lat1p, 24, 40);

    // 3) CARAFE u0: comp0 -> enc0(bf16) + fpn1 backfill -> carafe0
    conv1x1_mfma<64, 32, 1, true><<<dim3(120, 1, 4), blk, 0, stream>>>(
        nullptr, lat1p, u0_comp_w, u0_comp_g, u0_comp_bt, u0_comp_m, u0_comp_v,
        compp, 48 * 80);
    enc_fpn<<<dim3(660), blk, 0, stream>>>(420,
        compp, wt_enc0, u0_enc_g, u0_enc_bt, u0_enc_m, u0_enc_v, enc_us, 48, 80, 5,
        lat1p, wt_fpn1, fpn1_b, out1, 48, 80, 5);
    carafe_kernel<2><<<dim3(10, 6, 8), blk, 0, stream>>>(lat1p, enc_us, lat0b, lat0p, 48, 80);

    // 4) final fpn: level0 only (960 blocks)
    fpn_multi<<<dim3(960), blk, 0, stream>>>(lat0p, wt_fpn0, fpn0_b, out0);
}

// Round 15
// 243.482 us; speedup vs baseline: 1.0297x; 1.0297x over previous
//
#include <hip/hip_runtime.h>

#define BN_EPS 1e-5f

typedef __attribute__((ext_vector_type(8))) short bf16x8;
typedef __attribute__((ext_vector_type(4))) float f32x4;

__device__ __forceinline__ unsigned short f2bf(float f) {
    unsigned u = __float_as_uint(f);
    return (unsigned short)((u + 0x7fffu + ((u >> 16) & 1u)) >> 16);   // RNE
}
__device__ __forceinline__ unsigned packbf(float lo, float hi) {
    return ((unsigned)f2bf(hi) << 16) | (unsigned)f2bf(lo);
}
__device__ __forceinline__ float bf2f(unsigned short u) {
    return __uint_as_float((unsigned)u << 16);
}
// load 8 consecutive fp32 weights, convert to bf16x8 in-register
__device__ __forceinline__ bf16x8 ldw8(const float* p) {
    float4 a = *(const float4*)p;
    float4 b = *(const float4*)(p + 4);
    union { unsigned u[4]; bf16x8 v; } r;
    r.u[0] = packbf(a.x, a.y);
    r.u[1] = packbf(a.z, a.w);
    r.u[2] = packbf(b.x, b.y);
    r.u[3] = packbf(b.z, b.w);
    return r.v;
}

// ---------------------------------------------------------------------------
// Mirrors are CHANNEL-LAST: [b][H][W][cp=32] u32 (cp k = channels 2k,2k+1
// pair-packed bf16).  enc logits channel-last [b][h][w][100] ushort.
// R28: exact revert to R12 (verified 244.4us).  R14's cooperative-kernel
// fusion KILLED the harness (graph capture incompatible) — cooperative
// launches are BLACKLISTED in this harness.  R13's conv3x3 reg-prefetch
// also reverted (regressed: single exposed round-trip was TLP-covered).
// ---------------------------------------------------------------------------

// ---------------------------------------------------------------------------
// conv3x3 body (bf16 MFMA 16x16x32, C_in=64, fp32 acc).  LDS 20736 B.
// Split-K staging; channel-last packed input.  OBF16: enc-logit bf16
// channel-last output.  CPB stays 1 (R1/R2 VGPR cliff).
// ---------------------------------------------------------------------------
template<int COP, int CSPLIT, int MODE, bool OBF16>
__device__ __forceinline__
void conv3x3_body(int rem, int TX, unsigned short* xs,
                  const unsigned* __restrict__ xp,
                  const unsigned short* __restrict__ wt,
                  const float* __restrict__ p0, const float* __restrict__ p1,
                  const float* __restrict__ p2, const float* __restrict__ p3,
                  float* __restrict__ out, unsigned short* __restrict__ out_us,
                  int H, int W, int C_out)
{
    constexpr int NP = 324;
    constexpr int CT = COP / 16;
    static_assert(CT == CSPLIT, "CPB must be 1 (R1/R2 VGPR cliff)");

    int cs = rem % CSPLIT;
    int b  = (rem / CSPLIT) & 3;
    int t  = rem / (CSPLIT * 4);
    int x0 = (t % TX) * 16, y0 = (t / TX) * 16;

    int tid  = threadIdx.x;
    int lane = tid & 63, wid = tid >> 6;
    int lrow = lane >> 4, lcol = lane & 15;
    int HWp = H * W;

    int co0 = cs * 16;
    bool colok = (x0 + lcol) < W;

    f32x4 accA[2], accB[2];
#pragma unroll
    for (int rr = 0; rr < 2; ++rr) {
        accA[rr] = (f32x4){0.f, 0.f, 0.f, 0.f};
        accB[rr] = (f32x4){0.f, 0.f, 0.f, 0.f};
    }

    unsigned int* wsl = (unsigned int*)xs;
    const unsigned* xb = xp + (size_t)b * HWp * 32;

#pragma unroll 1
    for (int kb = 0; kb < 2; ++kb) {
        if (kb) __syncthreads();          // protect xs before overwrite
        // ---- stage ch-pairs [kb*16, kb*16+16) of the 18x18 halo tile ----
        for (int it = tid; it < NP * 4; it += 256) {
            int p = it >> 2, g = it & 3;
            int py = p / 18, px = p - py * 18;
            int gy = y0 + py - 1, gx = x0 + px - 1;
            uint4 v = make_uint4(0u, 0u, 0u, 0u);
            if (gy >= 0 && gy < H && gx >= 0 && gx < W)
                v = *(const uint4*)(xb + ((size_t)gy * W + gx) * 32 + kb * 16 + g * 4);
            *(uint4*)(wsl + ((size_t)g * NP + p) * 4) = v;
        }
        __syncthreads();

        // ---- weights for this K-half: 9 taps x 1 frag ----
        bf16x8 a[9];
        const unsigned short* wl = wt + ((size_t)co0 + lcol) * 64 + kb * 32 + lrow * 8;
#pragma unroll
        for (int t9 = 0; t9 < 9; ++t9)
            a[t9] = *(const bf16x8*)(wl + (size_t)t9 * COP * 64);

        // ---- 18 MFMAs into persistent accumulators ----
#pragma unroll
        for (int rr = 0; rr < 2; ++rr) {
            int r0 = wid + rr * 8;
#pragma unroll
            for (int t9 = 0; t9 < 9; ++t9) {
                int dy = t9 / 3, dx = t9 - dy * 3;
                int g0 = lrow * NP + (r0 + dy) * 18 + lcol + dx;
                bf16x8 b0 = *(const bf16x8*)(xs + (size_t)g0 * 8);
                accA[rr] = __builtin_amdgcn_mfma_f32_16x16x32_bf16(a[t9], b0, accA[rr], 0, 0, 0);
                bf16x8 b1 = *(const bf16x8*)(xs + ((size_t)g0 + 4 * 18) * 8);
                accB[rr] = __builtin_amdgcn_mfma_f32_16x16x32_bf16(a[t9], b1, accB[rr], 0, 0, 0);
            }
        }
    }

    // ---- epilogue: BN/bias + store ----
    float sc[4], sh[4];
#pragma unroll
    for (int rg = 0; rg < 4; ++rg) {
        int co = co0 + lrow * 4 + rg;
        int cc = (co < C_out) ? co : 0;
        if (MODE == 0) { sc[rg] = 1.f; sh[rg] = p0[cc]; }
        else {
            float inv = p0[cc] * rsqrtf(p3[cc] + BN_EPS);
            sc[rg] = inv; sh[rg] = p1[cc] - p2[cc] * inv;
        }
    }
#pragma unroll
    for (int rr = 0; rr < 2; ++rr) {
        int r0 = wid + rr * 8;
        int yA = y0 + r0, yB = y0 + r0 + 4;
        if (OBF16) {
            if (colok) {
                if (yA < H) {
                    unsigned short* oc = out_us + (((size_t)b * H + yA) * W + x0 + lcol) * 100;
#pragma unroll
                    for (int rg = 0; rg < 4; ++rg) {
                        int co = co0 + lrow * 4 + rg;
                        if (co < C_out) oc[co] = f2bf(accA[rr][rg] * sc[rg] + sh[rg]);
                    }
                }
                if (yB < H) {
                    unsigned short* oc = out_us + (((size_t)b * H + yB) * W + x0 + lcol) * 100;
#pragma unroll
                    for (int rg = 0; rg < 4; ++rg) {
                        int co = co0 + lrow * 4 + rg;
                        if (co < C_out) oc[co] = f2bf(accB[rr][rg] * sc[rg] + sh[rg]);
                    }
                }
            }
        } else {
#pragma unroll
            for (int rg = 0; rg < 4; ++rg) {
                int co = co0 + lrow * 4 + rg;
                if (colok && co < C_out) {
                    float* oc = out + (((size_t)b * C_out + co) * H) * W + x0 + lcol;
                    if (yA < H) oc[(size_t)yA * W] = accA[rr][rg] * sc[rg] + sh[rg];
                    if (yB < H) oc[(size_t)yB * W] = accB[rr][rg] * sc[rg] + sh[rg];
                }
            }
        }
    }
}

// enc conv3x3 (channel-last packed in, bf16 channel-last out) + independent
// fpn level in ONE dispatch.
__global__ __launch_bounds__(256, 6)
void enc_fpn(int encBlocks,
             const unsigned* __restrict__ cxp, const unsigned short* __restrict__ wt_e,
             const float* __restrict__ g, const float* __restrict__ bt,
             const float* __restrict__ m, const float* __restrict__ v,
             unsigned short* __restrict__ enc_us, int He, int We, int TXe,
             const unsigned* __restrict__ xp, const unsigned short* __restrict__ wt_f,
             const float* __restrict__ bias, float* __restrict__ fout,
             int Hf, int Wf, int TXf)
{
    __shared__ unsigned short xs[4 * 324 * 8];
    int f = blockIdx.x;
    if (f < encBlocks)
        conv3x3_body<112, 7, 1, true>(f, TXe, xs, cxp, wt_e,
                                      g, bt, m, v, nullptr, enc_us, He, We, 100);
    else
        conv3x3_body<64, 4, 0, false>(f - encBlocks, TXf, xs, xp, wt_f,
                                      bias, nullptr, nullptr, nullptr, fout, nullptr, Hf, Wf, 64);
}

// final fpn: level0 only.  grid (960)
__global__ __launch_bounds__(256, 6)
void fpn_multi(const unsigned* __restrict__ l0p, const unsigned short* __restrict__ wt0,
               const float* __restrict__ b0, float* __restrict__ o0)
{
    __shared__ unsigned short xs[4 * 324 * 8];
    conv3x3_body<64, 4, 0, false>(blockIdx.x, 10, xs, l0p, wt0,
                                  b0, nullptr, nullptr, nullptr, o0, nullptr, 96, 160, 64);
}

// ---------------------------------------------------------------------------
// conv1x1 body (bf16 MFMA GEMM).  fp32 weights converted in-register (ldw8);
// output: channel-last bf16 pair-packed mirror.  INPK: channel-last packed
// input.  R25: DOUBLE-BUFFERED staging (stage(k+1) before MFMA(k)); one
// __syncthreads per K-step (buf[k&1] read in k, rewritten in k+2; the
// top-of-loop sync of k+1..k+2 orders it).  LDS = 2 buffers.
// ---------------------------------------------------------------------------
template<int C_IN, int NPX, int MODE, bool INPK>
__device__ __forceinline__
void conv1x1_body(int f, unsigned short* xs,
                  const float* __restrict__ x, const unsigned* __restrict__ xp,
                  const float* __restrict__ wf,
                  const float* __restrict__ p0, const float* __restrict__ p1,
                  const float* __restrict__ p2, const float* __restrict__ p3,
                  unsigned* __restrict__ outp, int HW)
{
    constexpr int NT = NPX / 16;
    constexpr int QUADS = NPX / 4;          // pow2
    constexpr int BUFU = NPX * 16;          // u32 per LDS buffer
    constexpr int NK = C_IN / 32;
    int nb = HW / NPX;
    int px0 = (f % nb) * NPX;
    int b   = f / nb;

    int tid = threadIdx.x;
    int lane = tid & 63, wid = tid >> 6;
    int lrow = lane >> 4, lcol = lane & 15;
    const float*    xb  = INPK ? nullptr : x + (size_t)b * C_IN * HW + px0;
    const unsigned* xpb = INPK ? xp + ((size_t)b * HW + px0) * 32 : nullptr;
    unsigned* xsu = (unsigned*)xs;

    auto stage = [&](int cc, int buf) {
        unsigned* base = xsu + buf * BUFU;
        if (INPK) {
            for (int it = tid; it < NPX * 4; it += 256) {
                int px = it >> 2, g = it & 3;
                uint4 v = *(const uint4*)(xpb + (size_t)px * 32 + cc / 2 + g * 4);
                *(uint4*)(base + ((size_t)g * NPX + px) * 4) = v;
            }
        } else {
            for (int j = tid; j < 16 * QUADS; j += 256) {
                int q  = j & (QUADS - 1);
                int cp = j / QUADS;
                int px = q * 4;
                const float* s0 = xb + (size_t)(cc + 2 * cp) * HW + px;
                float4 v0 = *(const float4*)s0;
                float4 v1 = *(const float4*)(s0 + HW);
                unsigned* wv = base + ((size_t)(cp >> 2) * NPX + px) * 4 + (cp & 3);
                wv[0]  = packbf(v0.x, v1.x);
                wv[4]  = packbf(v0.y, v1.y);
                wv[8]  = packbf(v0.z, v1.z);
                wv[12] = packbf(v0.w, v1.w);
            }
        }
    };

    f32x4 acc[NT];
#pragma unroll
    for (int nt = 0; nt < NT; ++nt) acc[nt] = (f32x4){0.f, 0.f, 0.f, 0.f};

    stage(0, 0);
#pragma unroll 1
    for (int k = 0; k < NK; ++k) {
        __syncthreads();
        if (k + 1 < NK) stage((k + 1) * 32, (k + 1) & 1);   // prefetch next step

        bf16x8 a = ldw8(wf + (size_t)(wid * 16 + lcol) * C_IN + k * 32 + lrow * 8);
        const unsigned short* rb = xs + (size_t)(k & 1) * BUFU * 2;
#pragma unroll
        for (int nt = 0; nt < NT; ++nt) {
            bf16x8 bf = *(const bf16x8*)(rb + ((size_t)lrow * NPX + nt * 16 + lcol) * 8);
            acc[nt] = __builtin_amdgcn_mfma_f32_16x16x32_bf16(a, bf, acc[nt], 0, 0, 0);
        }
    }

    // epilogue: channel-last mirror write — one uint2 per nt.
    float sc[4], sh[4];
#pragma unroll
    for (int rg = 0; rg < 4; ++rg) {
        int co = wid * 16 + lrow * 4 + rg;
        if (MODE == 0) { sc[rg] = 1.f; sh[rg] = p0[co]; }
        else {
            float inv = p0[co] * rsqrtf(p3[co] + BN_EPS);
            sc[rg] = inv; sh[rg] = p1[co] - p2[co] * inv;
        }
    }
    unsigned* pp = outp + ((size_t)b * HW + px0) * 32 + wid * 8 + lrow * 2;
#pragma unroll
    for (int nt = 0; nt < NT; ++nt) {
        float r[4];
#pragma unroll
        for (int rg = 0; rg < 4; ++rg) {
            r[rg] = acc[nt][rg] * sc[rg] + sh[rg];
            if (MODE == 1) r[rg] = fmaxf(r[rg], 0.f);
        }
        uint2 pk = make_uint2(packbf(r[0], r[1]), packbf(r[2], r[3]));
        *(uint2*)(pp + (size_t)(nt * 16 + lcol) * 32) = pk;
    }
}

// standalone conv1x1 (comp layers, channel-last packed in), grid (HW/NPX,1,B)
template<int C_IN, int NPX, int MODE, bool INPK>
__global__ __launch_bounds__(256, 4)
void conv1x1_mfma(const float* __restrict__ x, const unsigned* __restrict__ xp,
                  const float* __restrict__ wf,
                  const float* __restrict__ p0, const float* __restrict__ p1,
                  const float* __restrict__ p2, const float* __restrict__ p3,
                  unsigned* __restrict__ outp, int HW)
{
    __shared__ __align__(16) unsigned short xs[2 * 4 * NPX * 8];
    int nb = HW / NPX;
    int f = blockIdx.x + nb * blockIdx.z;
    conv1x1_body<C_IN, NPX, MODE, INPK>(f, xs, x, xp, wf, p0, p1, p2, p3, outp, HW);
}

// fused lateral convs + 3x3 weight prep backfill — ONE dispatch (894).
__global__ __launch_bounds__(256, 4)
void lat_prep(const float* __restrict__ x0, const float* __restrict__ w0,
              const float* __restrict__ b0, unsigned* __restrict__ lat0b,
              const float* __restrict__ x1, const float* __restrict__ w1,
              const float* __restrict__ b1, unsigned* __restrict__ lat1b,
              const float* __restrict__ x2, const float* __restrict__ w2,
              const float* __restrict__ b2, unsigned* __restrict__ lat2p,
              const float* __restrict__ f0w, const float* __restrict__ f1w,
              const float* __restrict__ f2w, const float* __restrict__ e0w,
              const float* __restrict__ e1w, unsigned short* __restrict__ wtb)
{
    __shared__ __align__(16) unsigned short xs[2 * 4 * 128 * 8];
    int f = blockIdx.x;
    if (f < 480)
        conv1x1_body<128, 128, 0, false>(f, xs, x0, nullptr, w0,
            b0, nullptr, nullptr, nullptr, lat0b, 15360);
    else if (f < 600)
        conv1x1_body<256, 128, 0, false>(f - 480, xs, x1, nullptr, w1,
            b1, nullptr, nullptr, nullptr, lat1b, 3840);
    else if (f < 660)
        conv1x1_body<512, 64, 0, false>(f - 600, xs, x2, nullptr, w2,
            b2, nullptr, nullptr, nullptr, lat2p, 960);
    else {
        int base = (f - 660) * 1024 + threadIdx.x;
#pragma unroll
        for (int t = 0; t < 4; ++t) {
            int i = base + t * 256;            // < 239616 exactly
            float v;
            if (i < 110592) {
                int z = i / 36864;
                int rem = i - z * 36864;
                int tap = rem / 4096;          // 64*64
                int r2 = rem - tap * 4096;
                int co = r2 >> 6, ci = r2 & 63;
                const float* src = (z == 0) ? f0w : (z == 1 ? f1w : f2w);
                v = src[((size_t)co * 64 + ci) * 9 + tap];
            } else {
                int j = i - 110592;
                int z = j / 64512;
                int rem = j - z * 64512;
                int tap = rem / 7168;          // 112*64
                int r2 = rem - tap * 7168;
                int co = r2 >> 6, ci = r2 & 63;
                const float* src = z ? e1w : e0w;
                v = (co < 100) ? src[((size_t)co * 64 + ci) * 9 + tap] : 0.f;
            }
            wtb[i] = f2bf(v);
        }
    }
}

// ---------------------------------------------------------------------------
// CARAFE (CGS=2).  channel-last src/base/dst; bf16 logits.
// grid: (2w/16, 2h/16, B * CGS), block 256
// ---------------------------------------------------------------------------
template<int CGS>
__global__ __launch_bounds__(256, 4)
void carafe_kernel(const unsigned* __restrict__ srcp,
                   const unsigned short* __restrict__ logits_us,
                   const unsigned* __restrict__ basep, unsigned* __restrict__ dstp,
                   int h, int w)
{
    constexpr int SW = 12, NPX = 144;
    constexpr int CH = 64 / CGS;     // channels per block
    constexpr int CP = CH / 2;       // channel-pairs per block
    constexpr int G  = CP / 4;       // uint4 groups per pixel
    constexpr int CS = CH + 4;
    __shared__ float ls[NPX * CS];

    int tid = threadIdx.x;
    int x0 = blockIdx.x * 16, y0 = blockIdx.y * 16;
    int b  = blockIdx.z / CGS;
    int cs = blockIdx.z % CGS;
    int H = 2 * h, W = 2 * w;
    int xs0 = (x0 >> 1) - 2, ys0 = (y0 >> 1) - 2;
    size_t hw = (size_t)h * w;
    const unsigned* sb = srcp + (size_t)b * hw * 32 + cs * CP;

    // stage: item = (p, g): uint4 of pairs cs*CP+4g..+3 at src pixel p.
    for (int i = tid; i < NPX * G; i += 256) {
        int p = i / G, g = i - (i / G) * G;
        int yy = p / SW, xx = p - yy * SW;
        int sy = ys0 + yy, sx = xs0 + xx;
        uint4 u = make_uint4(0u, 0u, 0u, 0u);
        if (sy >= 0 && sy < h && sx >= 0 && sx < w)
            u = *(const uint4*)(sb + ((size_t)sy * w + sx) * 32 + g * 4);
        float* lq = &ls[p * CS + g * 8];
        lq[0] = __uint_as_float(u.x << 16); lq[1] = __uint_as_float(u.x & 0xffff0000u);
        lq[2] = __uint_as_float(u.y << 16); lq[3] = __uint_as_float(u.y & 0xffff0000u);
        lq[4] = __uint_as_float(u.z << 16); lq[5] = __uint_as_float(u.z & 0xffff0000u);
        lq[6] = __uint_as_float(u.w << 16); lq[7] = __uint_as_float(u.w & 0xffff0000u);
    }
    __syncthreads();

    int lx = tid & 15, ty = tid >> 4;
    int x = x0 + lx, y = y0 + ty;
    int xw = x >> 1, yh = y >> 1;
    int par = (y & 1) * 2 + (x & 1);

    const unsigned short* lp = logits_us + ((size_t)b * hw + (size_t)yh * w + xw) * 100 + par;
    float l[25];
    float mx = -1e30f;
#pragma unroll
    for (int k = 0; k < 25; ++k) {
        l[k] = bf2f(lp[4 * k]);
        mx = fmaxf(mx, l[k]);
    }
    float s = 0.f;
#pragma unroll
    for (int k = 0; k < 25; ++k) {
        l[k] = __expf(l[k] - mx);
        s += l[k];
    }
    float invs = 1.f / s;
#pragma unroll
    for (int k = 0; k < 25; ++k) l[k] *= invs;

    int pb = (yh - ys0 - 2) * SW + (xw - xs0 - 2);

#pragma unroll 1
    for (int cg = 0; cg < CH / 16; ++cg) {
        float acc[16];
#pragma unroll
        for (int c = 0; c < 16; ++c) acc[c] = 0.f;
#pragma unroll
        for (int k = 0; k < 25; ++k) {
            int ti = k / 5, tj = k - ti * 5;
            const float* q = &ls[(pb + ti * SW + tj) * CS + cg * 16];
            float wk = l[k];
#pragma unroll
            for (int c = 0; c < 16; ++c)
                acc[c] = fmaf(wk, q[c], acc[c]);
        }
        // base/dst: 8 consecutive u32 at (px, pair base cs*CP+cg*8)
        size_t poff = (((size_t)b * H + y) * W + x) * 32 + cs * CP + cg * 8;
        uint4 ba = *(const uint4*)(basep + poff);
        uint4 bb = *(const uint4*)(basep + poff + 4);
        unsigned bu[8] = {ba.x, ba.y, ba.z, ba.w, bb.x, bb.y, bb.z, bb.w};
        unsigned ou[8];
#pragma unroll
        for (int j = 0; j < 8; ++j) {
            float n0 = __uint_as_float(bu[j] << 16) + acc[2 * j];
            float n1 = __uint_as_float(bu[j] & 0xffff0000u) + acc[2 * j + 1];
            ou[j] = packbf(n0, n1);
        }
        *(uint4*)(dstp + poff)     = make_uint4(ou[0], ou[1], ou[2], ou[3]);
        *(uint4*)(dstp + poff + 4) = make_uint4(ou[4], ou[5], ou[6], ou[7]);
    }
}

// ---------------------------------------------------------------------------
extern "C" void kernel_launch(void* const* d_in, const int* in_sizes, int n_in,
                              void* d_out, int out_size, void* d_ws, size_t ws_size,
                              hipStream_t stream)
{
    const float* x0      = (const float*)d_in[0];
    const float* lat0_w  = (const float*)d_in[1];
    const float* lat0_b  = (const float*)d_in[2];
    const float* fpn0_w  = (const float*)d_in[3];
    const float* fpn0_b  = (const float*)d_in[4];
    const float* x1      = (const float*)d_in[5];
    const float* lat1_w  = (const float*)d_in[6];
    const float* lat1_b  = (const float*)d_in[7];
    const float* fpn1_w  = (const float*)d_in[8];
    const float* fpn1_b  = (const float*)d_in[9];
    const float* x2      = (const float*)d_in[10];
    const float* lat2_w  = (const float*)d_in[11];
    const float* lat2_b  = (const float*)d_in[12];
    const float* fpn2_w  = (const float*)d_in[13];
    const float* fpn2_b  = (const float*)d_in[14];
    const float* u0_comp_w = (const float*)d_in[15];
    const float* u0_enc_w  = (const float*)d_in[16];
    const float* u0_comp_g  = (const float*)d_in[17];
    const float* u0_comp_bt = (const float*)d_in[18];
    const float* u0_comp_m  = (const float*)d_in[19];
    const float* u0_comp_v  = (const float*)d_in[20];
    const float* u0_enc_g   = (const float*)d_in[21];
    const float* u0_enc_bt  = (const float*)d_in[22];
    const float* u0_enc_m   = (const float*)d_in[23];
    const float* u0_enc_v   = (const float*)d_in[24];
    const float* u1_comp_w = (const float*)d_in[25];
    const float* u1_enc_w  = (const float*)d_in[26];
    const float* u1_comp_g  = (const float*)d_in[27];
    const float* u1_comp_bt = (const float*)d_in[28];
    const float* u1_comp_m  = (const float*)d_in[29];
    const float* u1_comp_v  = (const float*)d_in[30];
    const float* u1_enc_g   = (const float*)d_in[31];
    const float* u1_enc_bt  = (const float*)d_in[32];
    const float* u1_enc_m   = (const float*)d_in[33];
    const float* u1_enc_v   = (const float*)d_in[34];

    float* out = (float*)d_out;
    const size_t OUT0 = 4ull * 64 * 96 * 160;   // 3,932,160
    const size_t OUT1 = 4ull * 64 * 48 * 80;    //   983,040
    const size_t OUT2 = 4ull * 64 * 24 * 40;    //   245,760
    float* out0 = out;
    float* out1 = out + OUT0;
    float* out2 = out + OUT0 + OUT1;

    // workspace (mirrors are channel-last [b][H][W][cp=32] u32):
    unsigned* lat0b = (unsigned*)d_ws;                      // 1,966,080 u32
    unsigned* lat1b = lat0b + 1966080;                      //   491,520 u32
    unsigned short* wtb = (unsigned short*)(lat1b + 491520); // 239,616 bf16
    unsigned short* wt_fpn0 = wtb;
    unsigned short* wt_fpn1 = wtb + 36864;
    unsigned short* wt_fpn2 = wtb + 73728;
    unsigned short* wt_enc0 = wtb + 110592;
    unsigned short* wt_enc1 = wtb + 175104;
    unsigned* lat0p = (unsigned*)(wtb + 239616);            // 1,966,080 u32
    unsigned* lat1p = lat0p + 1966080;                      //   491,520 u32
    unsigned* lat2p = lat1p + 491520;                       //   122,880 u32
    unsigned* compp = lat2p + 122880;                       //   491,520 u32 (max)
    // out0 region doubles as scratch (fpn0 overwrites it LAST):
    unsigned short* enc_us = (unsigned short*)(out0 + OUT1); // enc logits bf16 CL

    dim3 blk(256);

    // 1) laterals (full-K, bias folded, mirror out) + 3x3 weight prep backfill
    lat_prep<<<dim3(894), blk, 0, stream>>>(
        x0, lat0_w, lat0_b, lat0b,
        x1, lat1_w, lat1_b, lat1b,
        x2, lat2_w, lat2_b, lat2p,
        fpn0_w, fpn1_w, fpn2_w, u0_enc_w, u1_enc_w, wtb);

    // 2) CARAFE u1: comp1 -> enc1(bf16) + fpn2 backfill -> carafe1
    conv1x1_mfma<64, 32, 1, true><<<dim3(30, 1, 4), blk, 0, stream>>>(
        nullptr, lat2p, u1_comp_w, u1_comp_g, u1_comp_bt, u1_comp_m, u1_comp_v,
        compp, 24 * 40);
    enc_fpn<<<dim3(264), blk, 0, stream>>>(168,
        compp, wt_enc1, u1_enc_g, u1_enc_bt, u1_enc_m, u1_enc_v, enc_us, 24, 40, 3,
        lat2p, wt_fpn2, fpn2_b, out2, 24, 40, 3);
    carafe_kernel<2><<<dim3(5, 3, 8), blk, 0, stream>>>(lat2p, enc_us, lat1b, lat1p, 24, 40);

    // 3) CARAFE u0: comp0 -> enc0(bf16) + fpn1 backfill -> carafe0
    conv1x1_mfma<64, 32, 1, true><<<dim3(120, 1, 4), blk, 0, stream>>>(
        nullptr, lat1p, u0_comp_w, u0_comp_g, u0_comp_bt, u0_comp_m, u0_comp_v,
        compp, 48 * 80);
    enc_fpn<<<dim3(660), blk, 0, stream>>>(420,
        compp, wt_enc0, u0_enc_g, u0_enc_bt, u0_enc_m, u0_enc_v, enc_us, 48, 80, 5,
        lat1p, wt_fpn1, fpn1_b, out1, 48, 80, 5);
    carafe_kernel<2><<<dim3(10, 6, 8), blk, 0, stream>>>(lat1p, enc_us, lat0b, lat0p, 48, 80);

    // 4) final fpn: level0 only (960 blocks)
    fpn_multi<<<dim3(960), blk, 0, stream>>>(lat0p, wt_fpn0, fpn0_b, out0);
}